// Round 9
// baseline (39.224 us; speedup 1.0000x reference)
//
#include <hip/hip_runtime.h>
#include <hip/hip_bf16.h>
#include <math.h>

// Problem constants (from reference setup_inputs)
constexpr int B_  = 192;
constexpr int NY  = 48;
constexpr int NT  = 48;
constexpr int C_  = 6625;
constexpr int EPB = NT * NY;               // 2304 elements per (b, array)

// DPP move helper (compile-time ctrl). Invalid/masked lanes get `identity`.
template<int CTRL, int RM>
__device__ __forceinline__ float dpp_movf(float identity, float x) {
    int r = __builtin_amdgcn_update_dpp(__builtin_bit_cast(int, identity),
                                        __builtin_bit_cast(int, x),
                                        CTRL, RM, 0xf, false);
    return __builtin_bit_cast(float, r);
}
// ctrl: ROW_SHR|n = 0x110|n, WAVE_SHR1 = 0x138, ROW_BCAST15 = 0x142, ROW_BCAST31 = 0x143

// ---- Node 2: gather across ALL 256 CUs (tests per-CU-MSHR scaling) ----
// One offset per thread; 1728 blocks self-balance across 256 CUs with a tiny
// work quantum. Cross-kernel visibility of ws is guaranteed by the runtime's
// inter-dispatch release/invalidate (no flags, no spins — R6/R7 lesson).
__global__ __launch_bounds__(256) void ep_gather(
    const float* __restrict__ pred,
    const float* __restrict__ I,
    const int*   __restrict__ tgt,
    float* __restrict__ wsP,
    float* __restrict__ wsI)
{
    int e = blockIdx.x * 256 + threadIdx.x;      // [0, 442368)
    int b = e / EPB;
    int i = e - b * EPB;
    int t = i / NY;
    int j = i - t * NY;
    int c = tgt[b * NT + t];
    size_t off = ((size_t)b * NY + (size_t)j) * C_ + (size_t)c;
    wsP[e] = fmaxf(__builtin_nontemporal_load(pred + off), 0.0f);
    wsI[e] = fmaxf(__builtin_nontemporal_load(I + off),    0.0f);   // compacted,
    // plain stores -> L2/L3-resident for the scan node (3.5 MB << 256 MB L3)
}

// ---- Node 3: per-b scan (validated DPP affine scan) + atomic mean ----
__global__ __launch_bounds__(256) void ep_scan(
    const float* __restrict__ R,
    const int*   __restrict__ tgt,
    const float* __restrict__ wsP,
    const float* __restrict__ wsI,
    float* __restrict__ out)
{
    __shared__ __align__(16) float sP[NT][NY];
    __shared__ __align__(16) float sI[NT][NY];
    __shared__ int sT[NT];

    const int b   = blockIdx.x;
    const int tid = threadIdx.x;

    if (tid < NT) sT[tid] = tgt[b * NT + tid];
    float R0 = 0.0f, R1v = 0.0f, R2v = 0.0f;
    if (tid < NY) {
        const float* Rb = R + ((size_t)b * NY + tid) * 3;
        R0  = Rb[0];
        R1v = Rb[1];
        R2v = Rb[2];
    }

    // Stage the compacted tile (2*9 KB) from L3-warm ws, float4-coalesced.
    const float4* p4 = (const float4*)(wsP + (size_t)b * EPB);
    const float4* i4 = (const float4*)(wsI + (size_t)b * EPB);
    float4* sp4 = (float4*)&sP[0][0];
    float4* si4 = (float4*)&sI[0][0];
    #pragma unroll
    for (int k = 0; k < 3; ++k) {
        int idx = tid + k * 256;
        if (idx < EPB / 4) {               // 576 float4 per array
            sp4[idx] = p4[idx];
            si4[idx] = i4[idx];
        }
    }
    __syncthreads();

    // Validated DPP affine-scan recurrence (wave 0, lanes 0..47).
    if (tid < NY) {
        const int j = tid;
        float Imult  = (j == NY - 1) ? 1.0f : R1v;
        float R2prev = dpp_movf<0x138, 0xf>(0.0f, R2v);   // R2[j-1]

        // row0: multiplicative scan of d0 = (tgt[0]==1) ? 1 : R2
        float d0 = (sT[0] == 1) ? 1.0f : R2v;
        float v  = (j == 0) ? 1.0f : d0;
        v *= dpp_movf<0x111, 0xf>(1.0f, v);
        v *= dpp_movf<0x112, 0xf>(1.0f, v);
        v *= dpp_movf<0x114, 0xf>(1.0f, v);
        v *= dpp_movf<0x118, 0xf>(1.0f, v);
        v *= dpp_movf<0x142, 0xa>(1.0f, v);
        v *= dpp_movf<0x143, 0xc>(1.0f, v);
        float row = v;

        float pg = sP[0][j];
        float ig = sI[0][j];
        for (int t = 0; t < NT - 1; ++t) {
            float pgn = sP[t + 1][j];      // prefetch next iteration
            float ign = sI[t + 1][j];

            // a[j] = row[j]*pI[j] + row[j-1]*pC[j-1]
            float u  = row * (R0 * pg);
            float up = dpp_movf<0x138, 0xf>(0.0f, u);
            float c  = fmaf(row, Imult * ig, up);
            float m  = (j == 0) ? 0.0f : ((sT[t + 1] == 1) ? 1.0f : R2prev);

            // inclusive affine-map scan (validated DPP pattern)
            { float mp = dpp_movf<0x111, 0xf>(1.0f, m), cp = dpp_movf<0x111, 0xf>(0.0f, c); c = fmaf(m, cp, c); m *= mp; }
            { float mp = dpp_movf<0x112, 0xf>(1.0f, m), cp = dpp_movf<0x112, 0xf>(0.0f, c); c = fmaf(m, cp, c); m *= mp; }
            { float mp = dpp_movf<0x114, 0xf>(1.0f, m), cp = dpp_movf<0x114, 0xf>(0.0f, c); c = fmaf(m, cp, c); m *= mp; }
            { float mp = dpp_movf<0x118, 0xf>(1.0f, m), cp = dpp_movf<0x118, 0xf>(0.0f, c); c = fmaf(m, cp, c); m *= mp; }
            { float mp = dpp_movf<0x142, 0xa>(1.0f, m), cp = dpp_movf<0x142, 0xa>(0.0f, c); c = fmaf(m, cp, c); m *= mp; }
            { float mp = dpp_movf<0x143, 0xc>(1.0f, m), cp = dpp_movf<0x143, 0xc>(0.0f, c); c = fmaf(m, cp, c); m *= mp; }
            row = c;

            pg = pgn; ig = ign;
        }

        // Tail: 192 time-scattered atomics (R8-proven), out zeroed by node 1.
        if (j == NY - 1) atomicAdd(out, logf(row) * (1.0f / (float)B_));
    }
}

extern "C" void kernel_launch(void* const* d_in, const int* in_sizes, int n_in,
                              void* d_out, int out_size, void* d_ws, size_t ws_size,
                              hipStream_t stream) {
    const float* pred = (const float*)d_in[0];
    const float* R    = (const float*)d_in[1];
    const float* I    = (const float*)d_in[2];
    const int*   tgt  = (const int*)d_in[3];
    float* out = (float*)d_out;

    char* ws = (char*)d_ws;
    float* wsP = (float*)(ws);                    // 442368 floats
    float* wsI = (float*)(ws + 1769472);          // 442368 floats

    hipMemsetAsync(out, 0, sizeof(float), stream);            // node 1
    ep_gather<<<(B_ * EPB) / 256, 256, 0, stream>>>(pred, I, tgt, wsP, wsI); // node 2
    ep_scan<<<B_, 256, 0, stream>>>(R, tgt, wsP, wsI, out);   // node 3
}